// Round 7
// baseline (97.089 us; speedup 1.0000x reference)
//
#include <hip/hip_runtime.h>
#include <stdint.h>

// Correlation layer: in1,in2 [8,256,128,128] f32 -> out [8,81,128,128] f32
// out[b, dy*9+dx, y, x] = mean_c in1[b,c,y,x] * in2pad[b,c,y+dy,x+dx], pad=4
//
// v7: persistent blocks. grid=256 (1/CU); each block runs 4 consecutive y-tiles
// with ONE continuous 32-chunk DMA pipeline (no per-tile prologue/tail bubbles).
// Per chunk: [A: issue DMA(c+2)+A(c+2); MFMA(c); vmcnt(14)+bar] [B: convert(c+1); lgkm+bar].
// Tile boundary: dsrc recomputed at k==6; epilogue(t) after k==7 barrier into a
// dedicated LDS scratch (no extra barriers); acc reset at tile top.

#define B_  8
#define C_  256
#define H_  128
#define W_  128
#define ND  9
#define TY  8
#define TW  16
#define NT  4                    // tiles per block
#define KC  32
#define KB  4                    // KC/8
#define RR  16                   // TY+8
#define JJ  24
#define NITEM 3                  // convert items per thread
#define NDMA  6                  // DMA issues per wave per chunk
#define CS   (H_ * W_)
#define NCH  8                   // chunks per tile
#define SBUF (KC * RR * JJ)      // floats per S buffer (48KB)
#define FBUF (KB * RR * JJ * 8)  // shorts per F buffer (24KB)
#define FOFF (2 * SBUF * 4)      // 98304
#define EPOFF (FOFF + 2 * FBUF * 2)        // 147456
#define LDS_TOTAL (EPOFF + 8 * 16 * JJ * 4) // 159744 bytes

typedef short v8s __attribute__((ext_vector_type(8)));
typedef float v4f __attribute__((ext_vector_type(4)));

__device__ __forceinline__ unsigned short f2bf(float f) {
    union { float f; unsigned u; } v; v.f = f;
    return (unsigned short)((v.u + 0x7FFFu + ((v.u >> 16) & 1u)) >> 16);
}

__device__ __forceinline__ void dma16(const float* g, void* lds) {
    __builtin_amdgcn_global_load_lds(
        (const __attribute__((address_space(1))) void*)g,
        (__attribute__((address_space(3))) void*)lds, 16, 0, 0);
}

#define FENCE()        asm volatile("" ::: "memory")
#define WAITV14_BAR()  asm volatile("s_waitcnt vmcnt(14)\n\ts_barrier" ::: "memory")
#define WAITV0_BAR()   asm volatile("s_waitcnt vmcnt(0)\n\ts_barrier" ::: "memory")
#define LGKM0_BAR()    asm volatile("s_waitcnt lgkmcnt(0)\n\ts_barrier" ::: "memory")
#define LGKM0()        asm volatile("s_waitcnt lgkmcnt(0)" ::: "memory")

__global__ __launch_bounds__(512, 2)
void corr_mfma_kernel(const float* __restrict__ in1,
                      const float* __restrict__ in2,
                      float* __restrict__ out) {
    extern __shared__ __align__(16) char ldsbase[];
    float* S  = (float*)ldsbase;                 // S[2][KC][RR][JJ] f32
    short* F  = (short*)(ldsbase + FOFF);        // F[2][KB][RR][JJ][8] bf16
    float* EP = (float*)(ldsbase + EPOFF);       // epilogue scratch, per-wave

    const int tid  = threadIdx.x;
    const int lane = tid & 63;
    const int w    = tid >> 6;

    // grid 256 = 8 batches (XCD-major) x 8 x-tiles x 4 y-strips
    const int lin = blockIdx.x;
    const int b   = lin & 7;                    // batch == XCD
    const int idx = lin >> 3;
    const int x0  = (idx & 7) * TW;
    int y0        = (idx >> 3) * (NT * TY);     // strip base; marches by 8

    const int i_px = lane & 15;
    const int kb   = lane >> 4;

    // ---- fixed per-granule DMA bases (y-independent) ----
    const float* dbase[NDMA];
    int drr[NDMA], ddst[NDMA];
    #pragma unroll
    for (int t = 0; t < NDMA; ++t) {
        const int q  = w * NDMA + t;
        const int g  = q * 64 + lane;
        const int cc = g / 96;                  // channel within chunk
        const int rm = g % 96;
        const int r  = rm / 6;                  // staged row 0..15
        const int jg = rm % 6;
        int gx = x0 - 4 + jg * 4;
        gx = gx < 0 ? 0 : (gx > W_ - 4 ? W_ - 4 : gx);
        dbase[t] = in2 + (long)(b * C_ + cc) * CS + gx;
        drr[t]   = r;
        ddst[t]  = q * 1024;
    }
    const float* dsrc[NDMA];
    #pragma unroll
    for (int t = 0; t < NDMA; ++t) {            // tile-0 descriptors
        int gy = y0 - 4 + drr[t];
        gy = gy < 0 ? 0 : (gy > H_ - 1 ? H_ - 1 : gy);
        dsrc[t] = dbase[t] + (long)gy * W_;
    }

    // ---- convert-pass descriptors (y-part resolved per chunk) ----
    int soff[NITEM], foff2[NITEM], irr[NITEM];
    bool vx[NITEM];
    #pragma unroll
    for (int it = 0; it < NITEM; ++it) {
        const int s   = tid + it * 512;
        const int ikb = s / (RR * JJ);
        const int ir  = (s / JJ) % RR;
        const int ij  = s % JJ;
        soff[it]  = ikb * 8 * (RR * JJ) + ir * JJ + ij;
        foff2[it] = s * 8;
        irr[it]   = ir;
        vx[it]    = (unsigned)(x0 - 4 + ij) < (unsigned)W_;
    }

    const float* p1 =
        in1 + ((long)b * C_ + kb * 8) * CS + (long)(y0 + w) * W_ + x0 + i_px;

    v4f acc0[ND];
    v4f acc1[5];
    float a_buf[2][8];
    v8s afrag, afrag_nxt;

    // ---- prologue: chunks 0,1 of tile 0 ----
    #pragma unroll
    for (int t = 0; t < NDMA; ++t) dma16(dsrc[t], (char*)S + ddst[t]);
    #pragma unroll
    for (int e = 0; e < 8; ++e) a_buf[0][e] = p1[(long)e * CS];
    FENCE();
    #pragma unroll
    for (int t = 0; t < NDMA; ++t)
        dma16(dsrc[t] + (long)KC * CS, (char*)S + SBUF * 4 + ddst[t]);
    #pragma unroll
    for (int e = 0; e < 8; ++e) a_buf[1][e] = p1[(long)KC * CS + (long)e * CS];
    FENCE();
    WAITV14_BAR();                   // all waves' chunk-0 DMA landed
    #pragma unroll
    for (int e = 0; e < 8; ++e) afrag[e] = (short)f2bf(a_buf[0][e]);
    {
        const int y04 = y0 - 4;
        v8s pk[NITEM];
        #pragma unroll
        for (int it = 0; it < NITEM; ++it) {
            #pragma unroll
            for (int e = 0; e < 8; ++e)
                pk[it][e] = (short)f2bf(S[soff[it] + e * (RR * JJ)]);
            if (!(vx[it] && (unsigned)(y04 + irr[it]) < (unsigned)H_)) pk[it] = (v8s)0;
        }
        #pragma unroll
        for (int it = 0; it < NITEM; ++it)
            *(v8s*)&F[foff2[it]] = pk[it];
    }
    LGKM0_BAR();                     // F(0) visible

    // ---- 4 tiles, one continuous pipeline ----
    #pragma unroll 1
    for (int tt = 0; tt < NT; ++tt) {
        #pragma unroll
        for (int d = 0; d < ND; ++d) acc0[d] = (v4f)0.0f;
        #pragma unroll
        for (int p = 0; p < 5; ++p)  acc1[p] = (v4f)0.0f;

        #pragma unroll
        for (int k = 0; k < NCH; ++k) {
            const int cb = k & 1;
            const bool last_tile  = (tt == NT - 1);
            const bool has_issue  = (k < 6) || !last_tile;
            const bool last_chunk = last_tile && (k == 7);

            // ---- region A: issue chunk c+2; MFMA chunk c ----
            if (k == 6 && !last_tile) {          // descriptors -> next tile
                #pragma unroll
                for (int t = 0; t < NDMA; ++t) {
                    int gy = y0 + TY - 4 + drr[t];
                    gy = gy < 0 ? 0 : (gy > H_ - 1 ? H_ - 1 : gy);
                    dsrc[t] = dbase[t] + (long)gy * W_;
                }
            }
            if (k < 6) {
                const long co = (long)(k + 2) * KC * CS;
                #pragma unroll
                for (int t = 0; t < NDMA; ++t)
                    dma16(dsrc[t] + co, (char*)S + cb * (SBUF * 4) + ddst[t]);
                #pragma unroll
                for (int e = 0; e < 8; ++e) a_buf[cb][e] = p1[co + (long)e * CS];
                FENCE();
            } else if (!last_tile) {
                const long co = (long)(k - 6) * KC * CS;   // next tile ch 0/1
                const float* p1n = p1 + TY * W_;
                #pragma unroll
                for (int t = 0; t < NDMA; ++t)
                    dma16(dsrc[t] + co, (char*)S + cb * (SBUF * 4) + ddst[t]);
                #pragma unroll
                for (int e = 0; e < 8; ++e) a_buf[cb][e] = p1n[co + (long)e * CS];
                FENCE();
            }

            #pragma unroll
            for (int dy = 0; dy < ND; ++dy) {
                const int r = w + dy;
                const v8s bf = *(const v8s*)&F[cb * FBUF + ((kb * RR + r) * JJ + i_px) * 8];
                acc0[dy] = __builtin_amdgcn_mfma_f32_16x16x32_bf16(afrag, bf, acc0[dy], 0, 0, 0);
            }
            #pragma unroll
            for (int P = 0; P < 5; ++P) {
                int r = w + 2 * P + (i_px >> 3);
                if (r > RR - 1) r = RR - 1;
                const int j = 16 + (i_px & 7);
                const v8s bf = *(const v8s*)&F[cb * FBUF + ((kb * RR + r) * JJ + j) * 8];
                acc1[P] = __builtin_amdgcn_mfma_f32_16x16x32_bf16(afrag, bf, acc1[P], 0, 0, 0);
            }

            // ---- wait + region B: convert chunk c+1 ----
            if (!last_chunk) {
                if (has_issue) { WAITV14_BAR(); } else { WAITV0_BAR(); }

                #pragma unroll
                for (int e = 0; e < 8; ++e) afrag_nxt[e] = (short)f2bf(a_buf[cb ^ 1][e]);
                const int y04 = y0 + ((k == 7) ? TY : 0) - 4;   // tile of chunk c+1
                v8s pk[NITEM];
                #pragma unroll
                for (int it = 0; it < NITEM; ++it) {
                    #pragma unroll
                    for (int e = 0; e < 8; ++e)
                        pk[it][e] = (short)f2bf(S[(cb ^ 1) * SBUF + soff[it] + e * (RR * JJ)]);
                    if (!(vx[it] && (unsigned)(y04 + irr[it]) < (unsigned)H_)) pk[it] = (v8s)0;
                }
                #pragma unroll
                for (int it = 0; it < NITEM; ++it)
                    *(v8s*)&F[(cb ^ 1) * FBUF + foff2[it]] = pk[it];
                afrag = afrag_nxt;

                LGKM0_BAR();
            }

            // ---- epilogue for tile tt (wave-private EP scratch, no barriers) ----
            if (k == 7) {
                float* epw = EP + w * (16 * JJ);
                const int g = lane >> 4;
                for (int dy = 0; dy < ND; ++dy) {
                    #pragma unroll
                    for (int q = 0; q < 4; ++q)
                        epw[(g * 4 + q) * JJ + i_px] = acc0[dy][q];
                    if ((i_px >> 3) == (dy & 1)) {
                        #pragma unroll
                        for (int q = 0; q < 4; ++q)
                            epw[(g * 4 + q) * JJ + 16 + (i_px & 7)] = acc1[dy >> 1][q];
                    }
                    LGKM0();
                    #pragma unroll
                    for (int rep = 0; rep < 3; ++rep) {
                        const int dx = g + rep * 4;
                        if (dx < 9) {
                            const float v = epw[i_px * JJ + i_px + dx] * (1.0f / 256.0f);
                            out[((((long)b * 81) + dy * 9 + dx) * H_ + (y0 + w)) * W_ + x0 + i_px] = v;
                        }
                    }
                    LGKM0();
                }
            }
        }
        y0 += TY;
        p1 += TY * W_;
    }
}

extern "C" void kernel_launch(void* const* d_in, const int* in_sizes, int n_in,
                              void* d_out, int out_size, void* d_ws, size_t ws_size,
                              hipStream_t stream) {
    const float* in1 = (const float*)d_in[0];
    const float* in2 = (const float*)d_in[1];
    float* outp      = (float*)d_out;
    (void)hipFuncSetAttribute((const void*)corr_mfma_kernel,
                              hipFuncAttributeMaxDynamicSharedMemorySize,
                              LDS_TOTAL);
    corr_mfma_kernel<<<256, 512, LDS_TOTAL, stream>>>(in1, in2, outp);
}